// Round 1
// baseline (293.480 us; speedup 1.0000x reference)
//
#include <hip/hip_runtime.h>
#include <math.h>

#define NI 512
#define CC 512
#define KCL 64
#define HW49 49
#define CQ 25088   // 512*49

// Upsample matrix U[13][7], align_corners: even i -> 1 at i/2; odd i -> 0.5 at (i-1)/2,(i+1)/2
__device__ __forceinline__ float Uval(int i, int u) {
    if (i & 1) return (u == ((i - 1) >> 1) || u == ((i + 1) >> 1)) ? 0.5f : 0.0f;
    return (u == (i >> 1)) ? 1.0f : 0.0f;
}

// ---------------- K_G: build per-channel 49x49 operator ----------------
__global__ __launch_bounds__(256) void kG(
    const float* __restrict__ c3w, const float* __restrict__ c5w, const float* __restrict__ c7w,
    const float* __restrict__ dww, const float* __restrict__ dhw, const float* __restrict__ accw,
    float* __restrict__ Gmat)
{
    const int c = blockIdx.x;
    const int t = threadIdx.x;
    __shared__ float dh[91], dw[91];
    __shared__ float Fh3[147], Fw3[147], Fh5[245], Fw5[245], Fh7[343], Fw7[343];
    __shared__ float wa3[9], wa5[25], wa7[49];
    if (t < 91) dh[t] = dhw[t];
    if (t >= 128 && t < 219) dw[t - 128] = dww[t - 128];
    __syncthreads();
    for (int idx = t; idx < 147; idx += 256) {
        int oh = idx / 21, r = idx % 21, u = r / 3, dy = r % 3;
        float sh = 0.f, sw = 0.f;
        for (int i = 0; i < 13; i++) { int y = i - dy + 1; if (y >= 0 && y < 13) { float uu = Uval(i, u); sh += dh[oh * 13 + y] * uu; sw += dw[oh * 13 + y] * uu; } }
        Fh3[idx] = sh; Fw3[idx] = sw;
    }
    for (int idx = t; idx < 245; idx += 256) {
        int oh = idx / 35, r = idx % 35, u = r / 5, dy = r % 5;
        float sh = 0.f, sw = 0.f;
        for (int i = 0; i < 13; i++) { int y = i - dy + 2; if (y >= 0 && y < 13) { float uu = Uval(i, u); sh += dh[oh * 13 + y] * uu; sw += dw[oh * 13 + y] * uu; } }
        Fh5[idx] = sh; Fw5[idx] = sw;
    }
    for (int idx = t; idx < 343; idx += 256) {
        int oh = idx / 49, r = idx % 49, u = r / 7, dy = r % 7;
        float sh = 0.f, sw = 0.f;
        for (int i = 0; i < 13; i++) { int y = i - dy + 3; if (y >= 0 && y < 13) { float uu = Uval(i, u); sh += dh[oh * 13 + y] * uu; sw += dw[oh * 13 + y] * uu; } }
        Fh7[idx] = sh; Fw7[idx] = sw;
    }
    if (t < 9)               { float s = 0.f; for (int co = 0; co < 32; co++) s += accw[co]      * c3w[(size_t)(co * 512 + c) * 9  + t];        wa3[t] = s; }
    if (t >= 32 && t < 57)   { int q = t - 32; float s = 0.f; for (int co = 0; co < 32; co++) s += accw[32 + co] * c5w[(size_t)(co * 512 + c) * 25 + q]; wa5[q] = s; }
    if (t >= 64 && t < 113)  { int q = t - 64; float s = 0.f; for (int co = 0; co < 20; co++) s += accw[64 + co] * c7w[(size_t)(co * 512 + c) * 49 + q]; wa7[q] = s; }
    __syncthreads();
    for (int o = t; o < 2401; o += 256) {
        int q = o / 49, p = o % 49;
        int u = q / 7, v = q % 7, ow = p / 7, oh = p % 7;
        float acc = 0.f;
        #pragma unroll
        for (int dy = 0; dy < 3; dy++) { float fh = Fh3[(oh * 7 + u) * 3 + dy];
            #pragma unroll
            for (int dx = 0; dx < 3; dx++) acc += wa3[dy * 3 + dx] * fh * Fw3[(ow * 7 + v) * 3 + dx]; }
        #pragma unroll
        for (int dy = 0; dy < 5; dy++) { float fh = Fh5[(oh * 7 + u) * 5 + dy];
            #pragma unroll
            for (int dx = 0; dx < 5; dx++) acc += wa5[dy * 5 + dx] * fh * Fw5[(ow * 7 + v) * 5 + dx]; }
        #pragma unroll
        for (int dy = 0; dy < 7; dy++) { float fh = Fh7[(oh * 7 + u) * 7 + dy];
            #pragma unroll
            for (int dx = 0; dx < 7; dx++) acc += wa7[dy * 7 + dx] * fh * Fw7[(ow * 7 + v) * 7 + dx]; }
        Gmat[(size_t)c * 2401 + o] = acc;
    }
}

// ---------------- K_Cb: constant term of cw ----------------
__global__ void kCb(const float* __restrict__ c3b, const float* __restrict__ c5b, const float* __restrict__ c7b,
                    const float* __restrict__ dww, const float* __restrict__ dwb,
                    const float* __restrict__ dhw, const float* __restrict__ dhb,
                    const float* __restrict__ accw, const float* __restrict__ accb,
                    float* __restrict__ Cb)
{
    __shared__ float A0s, A1s, Sdw[7], Sdh[7];
    int t = threadIdx.x;
    if (t == 0) {
        float a0 = 0.f, a1 = 0.f;
        for (int co = 0; co < 84; co++) {
            float aw = accw[co]; a0 += aw;
            float b = (co < 32) ? c3b[co] : ((co < 64) ? c5b[co - 32] : c7b[co - 64]);
            a1 += aw * b;
        }
        A0s = a0; A1s = a1;
    }
    if (t < 7)             { float s = 0.f; for (int xx = 0; xx < 13; xx++) s += dww[t * 13 + xx]; Sdw[t] = s; }
    if (t >= 8 && t < 15)  { int oh = t - 8; float s = 0.f; for (int y = 0; y < 13; y++) s += dhw[oh * 13 + y]; Sdh[oh] = s; }
    __syncthreads();
    if (t < 49) {
        int ow = t / 7, oh = t % 7;
        Cb[t] = A1s * Sdw[ow] * Sdh[oh] + A0s * (dwb[ow] * Sdh[oh] + dhb[oh]) + accb[0];
    }
}

// ---------------- K_hln: LayerNorm([7,7]) ----------------
__global__ __launch_bounds__(256) void kHln(const float* __restrict__ x,
    const float* __restrict__ lnw, const float* __restrict__ lnb, float* __restrict__ hln)
{
    int wid = (blockIdx.x << 2) + (threadIdx.x >> 6);
    int lane = threadIdx.x & 63;
    const float* xp = x + (size_t)wid * 49;
    float v = (lane < 49) ? xp[lane] : 0.f;
    float s = v, ss = v * v;
    #pragma unroll
    for (int off = 32; off >= 1; off >>= 1) { s += __shfl_xor(s, off, 64); ss += __shfl_xor(ss, off, 64); }
    float mu = s * (1.f / 49.f);
    float var = ss * (1.f / 49.f) - mu * mu;
    float rs = 1.f / sqrtf(var + 1e-5f);
    if (lane < 49)
        hln[(size_t)wid * 49 + lane] = (v - mu) * rs * lnw[lane] + lnb[lane];
}

// ---------------- K_cw1: partial GEMM  cw_partial = hln x Gmat ----------------
__global__ __launch_bounds__(64) void kCw1(const float* __restrict__ hln,
    const float* __restrict__ Gmat, float* __restrict__ part)
{
    __shared__ float As[64 * 53];
    __shared__ float Gs[49 * 68];
    const int b = blockIdx.x;
    const int nt = b >> 7, ks = b & 127;
    const int n0 = nt * 64;
    const int cq0 = ks * 196;
    const int t = threadIdx.x;
    const int ng = t >> 2, pg = t & 3;
    float acc[4][16];
    #pragma unroll
    for (int j = 0; j < 4; j++)
        #pragma unroll
        for (int m = 0; m < 16; m++) acc[j][m] = 0.f;
    for (int kk = 0; kk < 4; kk++) {
        const int kb = cq0 + kk * 49;
        for (int i = t; i < 3136; i += 64) { int nr = i / 49, kc = i % 49; As[nr * 53 + kc] = hln[(size_t)(n0 + nr) * CQ + kb + kc]; }
        for (int i = t; i < 2401; i += 64) { Gs[(i / 49) * 68 + (i % 49)] = Gmat[(size_t)kb * 49 + i]; }
        __syncthreads();
        for (int k = 0; k < 49; k++) {
            const float* gp = &Gs[k * 68 + 16 * pg];
            float4 g0 = *(const float4*)(gp + 0);
            float4 g1 = *(const float4*)(gp + 4);
            float4 g2 = *(const float4*)(gp + 8);
            float4 g3 = *(const float4*)(gp + 12);
            #pragma unroll
            for (int j = 0; j < 4; j++) {
                float a = As[(4 * ng + j) * 53 + k];
                acc[j][0]  += a * g0.x; acc[j][1]  += a * g0.y; acc[j][2]  += a * g0.z; acc[j][3]  += a * g0.w;
                acc[j][4]  += a * g1.x; acc[j][5]  += a * g1.y; acc[j][6]  += a * g1.z; acc[j][7]  += a * g1.w;
                acc[j][8]  += a * g2.x; acc[j][9]  += a * g2.y; acc[j][10] += a * g2.z; acc[j][11] += a * g2.w;
                acc[j][12] += a * g3.x; acc[j][13] += a * g3.y; acc[j][14] += a * g3.z; acc[j][15] += a * g3.w;
            }
        }
        __syncthreads();
    }
    #pragma unroll
    for (int j = 0; j < 4; j++) {
        int n = n0 + 4 * ng + j;
        #pragma unroll
        for (int m = 0; m < 16; m++) {
            int p = 16 * pg + m;
            if (p < 49) part[(size_t)ks * CQ + (size_t)n * 49 + p] = acc[j][m];
        }
    }
}

// ---------------- K_cw2: reduce partials + Cb ----------------
__global__ __launch_bounds__(256) void kCw2(const float* __restrict__ part, const float* __restrict__ Cb,
                                            float* __restrict__ cw)
{
    int o = blockIdx.x * 256 + threadIdx.x;
    if (o >= CQ) return;
    int p = o % 49;
    float s = Cb[p];
    for (int ks = 0; ks < 128; ks++) s += part[(size_t)ks * CQ + o];
    cw[o] = s;
}

// ---------------- K_sm: channel norms + logits + softmax + mask ----------------
__global__ __launch_bounds__(256, 1) void kSm(const float* __restrict__ x,
    const float* __restrict__ convw, const float* __restrict__ convb,
    const float* __restrict__ cwg, float* __restrict__ maskr, float* __restrict__ msum)
{
    __shared__ float smx[25600];            // xT [l][516] (49 rows); reused as partial [8][64][50]
    __shared__ float lg[64 * 52];
    __shared__ float rn[49], cwl[49], smaxs[49], sinv[49], cb[64];
    const int n = blockIdx.x;
    const int t = threadIdx.x;
    const float* xp = x + (size_t)n * CQ;
    for (int i = t; i < CQ; i += 256) { int c = i / 49, l = i % 49; smx[l * 516 + c] = xp[i]; }
    if (t < 49) cwl[t] = cwg[n * 49 + t];
    if (t < 64) cb[t] = convb[t];
    __syncthreads();
    if (t < 196) {
        int l = t % 49, cq = t / 49;
        float s = 0.f;
        for (int c = cq * 128; c < cq * 128 + 128; c++) { float v = smx[l * 516 + c]; s += v * v; }
        lg[l * 4 + cq] = s;
    }
    __syncthreads();
    if (t < 49) {
        float s = lg[t * 4] + lg[t * 4 + 1] + lg[t * 4 + 2] + lg[t * 4 + 3];
        rn[t] = 1.f / fmaxf(sqrtf(s), 1e-12f);
    }
    __syncthreads();
    const int cs = t >> 5, kg = (t >> 2) & 7, lq = t & 3;
    float acc[8][13];
    #pragma unroll
    for (int j = 0; j < 8; j++)
        #pragma unroll
        for (int i = 0; i < 13; i++) acc[j][i] = 0.f;
    for (int m = 0; m < 16; m++) {
        const int c4 = cs * 4 + m * 32;
        float4 w[8];
        #pragma unroll
        for (int j = 0; j < 8; j++) w[j] = *(const float4*)&convw[(size_t)(kg * 8 + j) * 512 + c4];
        #pragma unroll
        for (int i = 0; i < 13; i++) {
            const int l = lq * 13 + i;
            const int li = (l < 49) ? l : 48;
            float4 xv = *(const float4*)&smx[li * 516 + c4];
            #pragma unroll
            for (int j = 0; j < 8; j++)
                acc[j][i] += w[j].x * xv.x + w[j].y * xv.y + w[j].z * xv.z + w[j].w * xv.w;
        }
    }
    __syncthreads();   // all xT reads complete before reuse
    #pragma unroll
    for (int j = 0; j < 8; j++) {
        int k = kg * 8 + j;
        #pragma unroll
        for (int i = 0; i < 13; i++) {
            int l = lq * 13 + i;
            if (l < 49) smx[cs * 3200 + k * 50 + l] = acc[j][i];
        }
    }
    __syncthreads();
    for (int o = t; o < 3136; o += 256) {
        int k = o / 49, l = o % 49;
        float s = 0.f;
        #pragma unroll
        for (int q = 0; q < 8; q++) s += smx[q * 3200 + k * 50 + l];
        lg[k * 52 + l] = s * rn[l] + cb[k];
    }
    __syncthreads();
    if (t < 49) {
        float m = -3.402823466e38f;
        for (int k = 0; k < 64; k++) m = fmaxf(m, lg[k * 52 + t]);
        float s = 0.f;
        for (int k = 0; k < 64; k++) s += __expf(lg[k * 52 + t] - m);
        smaxs[t] = m; sinv[t] = 1.f / s;
    }
    __syncthreads();
    for (int o = t; o < 3136; o += 256) {
        int k = o / 49, l = o % 49;
        float sa = __expf(lg[k * 52 + l] - smaxs[l]) * sinv[l];
        lg[k * 52 + l] = sa * cwl[l];
    }
    __syncthreads();
    if (t < 64) {
        float s = 0.f;
        for (int l = 0; l < 49; l++) s += lg[t * 52 + l];
        msum[n * 64 + t] = s;
    }
    for (int o = t; o < 3136; o += 256) {
        int k = o / 49, l = o % 49;
        maskr[(size_t)n * 3136 + o] = lg[k * 52 + l] * rn[l];
    }
}

// ---------------- K_vlad: aggregation + intra-norm + global norm ----------------
__global__ __launch_bounds__(512, 2) void kVlad(const float* __restrict__ x,
    const float* __restrict__ maskr, const float* __restrict__ msum,
    const float* __restrict__ cent, float* __restrict__ out)
{
    __shared__ float xb[512 * 52];
    __shared__ float mk[64 * 52];
    __shared__ float msL[64], ssq[64], scl[64];
    const int n = blockIdx.x;
    const int t = threadIdx.x;
    const float* xp = x + (size_t)n * CQ;
    for (int i = t; i < CQ; i += 512) { int c = i / 49, l = i % 49; xb[c * 52 + l] = xp[i]; }
    for (int i = t; i < 1536; i += 512) { int c = i / 3, l = 49 + i % 3; xb[c * 52 + l] = 0.f; }
    for (int i = t; i < 3136; i += 512) { mk[(i / 49) * 52 + (i % 49)] = maskr[(size_t)n * 3136 + i]; }
    for (int i = t; i < 192; i += 512) { mk[(i / 3) * 52 + 49 + i % 3] = 0.f; }
    if (t < 64) msL[t] = msum[n * 64 + t];
    __syncthreads();
    const int kg = t >> 6, cg = t & 63;
    float acc[8][8];
    #pragma unroll
    for (int j = 0; j < 8; j++)
        #pragma unroll
        for (int ci = 0; ci < 8; ci++) acc[j][ci] = 0.f;
    float msr[8];
    #pragma unroll
    for (int j = 0; j < 8; j++) msr[j] = msL[kg * 8 + j];
    for (int l4 = 0; l4 < 13; l4++) {
        float4 mv[8], xv[8];
        #pragma unroll
        for (int j = 0; j < 8; j++) mv[j] = *(const float4*)&mk[(kg * 8 + j) * 52 + l4 * 4];
        #pragma unroll
        for (int ci = 0; ci < 8; ci++) xv[ci] = *(const float4*)&xb[(cg + 64 * ci) * 52 + l4 * 4];
        #pragma unroll
        for (int j = 0; j < 8; j++)
            #pragma unroll
            for (int ci = 0; ci < 8; ci++)
                acc[j][ci] += mv[j].x * xv[ci].x + mv[j].y * xv[ci].y + mv[j].z * xv[ci].z + mv[j].w * xv[ci].w;
    }
    float ssr[8];
    #pragma unroll
    for (int j = 0; j < 8; j++) {
        int k = kg * 8 + j;
        float s = 0.f;
        #pragma unroll
        for (int ci = 0; ci < 8; ci++) {
            int c = cg + 64 * ci;
            float v = acc[j][ci] - cent[(size_t)k * 512 + c] * msr[j];
            acc[j][ci] = v; s += v * v;
        }
        ssr[j] = s;
    }
    #pragma unroll
    for (int j = 0; j < 8; j++)
        for (int off = 32; off >= 1; off >>= 1) ssr[j] += __shfl_xor(ssr[j], off, 64);
    if (cg == 0) {
        #pragma unroll
        for (int j = 0; j < 8; j++) ssq[kg * 8 + j] = ssr[j];
    }
    __syncthreads();
    if (t < 64) {
        float nrm = sqrtf(ssq[t]);
        float inv = 1.f / fmaxf(nrm, 1e-12f);
        float sk = nrm * inv;
        float g = sk * sk;
        #pragma unroll
        for (int off = 32; off >= 1; off >>= 1) g += __shfl_xor(g, off, 64);
        scl[t] = inv * (1.f / fmaxf(sqrtf(g), 1e-12f));
    }
    __syncthreads();
    float s2[8];
    #pragma unroll
    for (int j = 0; j < 8; j++) s2[j] = scl[kg * 8 + j];
    #pragma unroll
    for (int j = 0; j < 8; j++) {
        int k = kg * 8 + j;
        #pragma unroll
        for (int ci = 0; ci < 8; ci++)
            out[(size_t)n * 32768 + (size_t)k * 512 + cg + 64 * ci] = acc[j][ci] * s2[j];
    }
}

extern "C" void kernel_launch(void* const* d_in, const int* in_sizes, int n_in,
                              void* d_out, int out_size, void* d_ws, size_t ws_size,
                              hipStream_t stream)
{
    const float* x     = (const float*)d_in[0];
    const float* cent  = (const float*)d_in[1];
    const float* convw = (const float*)d_in[2];
    const float* convb = (const float*)d_in[3];
    const float* lnw   = (const float*)d_in[4];
    const float* lnb   = (const float*)d_in[5];
    const float* c3w   = (const float*)d_in[6];
    const float* c3b   = (const float*)d_in[7];
    const float* c5w   = (const float*)d_in[8];
    const float* c5b   = (const float*)d_in[9];
    const float* c7w   = (const float*)d_in[10];
    const float* c7b   = (const float*)d_in[11];
    const float* dww   = (const float*)d_in[12];
    const float* dwb   = (const float*)d_in[13];
    const float* dhw   = (const float*)d_in[14];
    const float* dhb   = (const float*)d_in[15];
    const float* accw  = (const float*)d_in[16];
    const float* accb  = (const float*)d_in[17];
    float* out = (float*)d_out;

    char* ws = (char*)d_ws;
    float* Gmat  = (float*)(ws);                    // 512*2401*4 = 4,917,248
    float* Cb    = (float*)(ws + 4917248);          // 256
    float* cw    = (float*)(ws + 4917504);          // 512*49*4 = 100,352
    float* hln   = (float*)(ws + 5017856);          // 51,380,224
    float* part  = (float*)(ws + 56398080);         // 128*25088*4 = 12,845,056  (end 69,243,136)
    float* maskr = hln;                              // hln dead after kCw1 -> overlay
    float* msum  = hln + 1605632;                    // after maskr (512*3136 floats)

    kG  <<<512,  256, 0, stream>>>(c3w, c5w, c7w, dww, dhw, accw, Gmat);
    kCb <<<1,    64,  0, stream>>>(c3b, c5b, c7b, dww, dwb, dhw, dhb, accw, accb, Cb);
    kHln<<<65536,256, 0, stream>>>(x, lnw, lnb, hln);
    kCw1<<<1024, 64,  0, stream>>>(hln, Gmat, part);
    kCw2<<<98,   256, 0, stream>>>(part, Cb, cw);
    kSm <<<512,  256, 0, stream>>>(x, convw, convb, cw, maskr, msum);
    kVlad<<<512, 512, 0, stream>>>(x, maskr, msum, cent, out);
}

// Round 3
// 257.087 us; speedup vs baseline: 1.1416x; 1.1416x over previous
//
#include <hip/hip_runtime.h>
#include <math.h>

#define NI 512
#define CC 512
#define KCL 64
#define HW49 49
#define CQ 25088   // 512*49
#define XP 516     // xT row pitch (floats), 4*odd -> 8 bank-groups

// Upsample matrix U[13][7], align_corners: even i -> 1 at i/2; odd i -> 0.5 at (i-1)/2,(i+1)/2
__device__ __forceinline__ float Uval(int i, int u) {
    if (i & 1) return (u == ((i - 1) >> 1) || u == ((i + 1) >> 1)) ? 0.5f : 0.0f;
    return (u == (i >> 1)) ? 1.0f : 0.0f;
}

// ---------------- K_G: build per-channel 49x49 operator (lnw folded in, lnb -> Gl) ----------------
__global__ __launch_bounds__(256) void kG(
    const float* __restrict__ c3w, const float* __restrict__ c5w, const float* __restrict__ c7w,
    const float* __restrict__ dww, const float* __restrict__ dhw, const float* __restrict__ accw,
    const float* __restrict__ lnw, const float* __restrict__ lnb,
    float* __restrict__ Gmat, float* __restrict__ Gl)
{
    const int c = blockIdx.x;
    const int t = threadIdx.x;
    __shared__ float dh[91], dw[91];
    __shared__ float Fh3[147], Fw3[147], Fh5[245], Fw5[245], Fh7[343], Fw7[343];
    __shared__ float wa3[9], wa5[25], wa7[49];
    __shared__ float Gtmp[2401];
    if (t < 91) dh[t] = dhw[t];
    if (t >= 128 && t < 219) dw[t - 128] = dww[t - 128];
    __syncthreads();
    for (int idx = t; idx < 147; idx += 256) {
        int oh = idx / 21, r = idx % 21, u = r / 3, dy = r % 3;
        float sh = 0.f, sw = 0.f;
        for (int i = 0; i < 13; i++) { int y = i - dy + 1; if (y >= 0 && y < 13) { float uu = Uval(i, u); sh += dh[oh * 13 + y] * uu; sw += dw[oh * 13 + y] * uu; } }
        Fh3[idx] = sh; Fw3[idx] = sw;
    }
    for (int idx = t; idx < 245; idx += 256) {
        int oh = idx / 35, r = idx % 35, u = r / 5, dy = r % 5;
        float sh = 0.f, sw = 0.f;
        for (int i = 0; i < 13; i++) { int y = i - dy + 2; if (y >= 0 && y < 13) { float uu = Uval(i, u); sh += dh[oh * 13 + y] * uu; sw += dw[oh * 13 + y] * uu; } }
        Fh5[idx] = sh; Fw5[idx] = sw;
    }
    for (int idx = t; idx < 343; idx += 256) {
        int oh = idx / 49, r = idx % 49, u = r / 7, dy = r % 7;
        float sh = 0.f, sw = 0.f;
        for (int i = 0; i < 13; i++) { int y = i - dy + 3; if (y >= 0 && y < 13) { float uu = Uval(i, u); sh += dh[oh * 13 + y] * uu; sw += dw[oh * 13 + y] * uu; } }
        Fh7[idx] = sh; Fw7[idx] = sw;
    }
    if (t < 9)               { float s = 0.f; for (int co = 0; co < 32; co++) s += accw[co]      * c3w[(size_t)(co * 512 + c) * 9  + t];        wa3[t] = s; }
    if (t >= 32 && t < 57)   { int q = t - 32; float s = 0.f; for (int co = 0; co < 32; co++) s += accw[32 + co] * c5w[(size_t)(co * 512 + c) * 25 + q]; wa5[q] = s; }
    if (t >= 64 && t < 113)  { int q = t - 64; float s = 0.f; for (int co = 0; co < 20; co++) s += accw[64 + co] * c7w[(size_t)(co * 512 + c) * 49 + q]; wa7[q] = s; }
    __syncthreads();
    for (int o = t; o < 2401; o += 256) {
        int q = o / 49, p = o % 49;
        int u = q / 7, v = q % 7, ow = p / 7, oh = p % 7;
        float acc = 0.f;
        #pragma unroll
        for (int dy = 0; dy < 3; dy++) { float fh = Fh3[(oh * 7 + u) * 3 + dy];
            #pragma unroll
            for (int dx = 0; dx < 3; dx++) acc += wa3[dy * 3 + dx] * fh * Fw3[(ow * 7 + v) * 3 + dx]; }
        #pragma unroll
        for (int dy = 0; dy < 5; dy++) { float fh = Fh5[(oh * 7 + u) * 5 + dy];
            #pragma unroll
            for (int dx = 0; dx < 5; dx++) acc += wa5[dy * 5 + dx] * fh * Fw5[(ow * 7 + v) * 5 + dx]; }
        #pragma unroll
        for (int dy = 0; dy < 7; dy++) { float fh = Fh7[(oh * 7 + u) * 7 + dy];
            #pragma unroll
            for (int dx = 0; dx < 7; dx++) acc += wa7[dy * 7 + dx] * fh * Fw7[(ow * 7 + v) * 7 + dx]; }
        Gtmp[o] = acc;
        Gmat[(size_t)c * 2401 + o] = acc * lnw[q];
    }
    __syncthreads();
    if (t < 49) {
        float s = 0.f;
        for (int q = 0; q < 49; q++) s += Gtmp[q * 49 + t] * lnb[q];
        Gl[c * 49 + t] = s;
    }
}

// ---------------- K_Cb: constant term of cw (incl. lnb fold via Gl) ----------------
__global__ void kCb(const float* __restrict__ c3b, const float* __restrict__ c5b, const float* __restrict__ c7b,
                    const float* __restrict__ dww, const float* __restrict__ dwb,
                    const float* __restrict__ dhw, const float* __restrict__ dhb,
                    const float* __restrict__ accw, const float* __restrict__ accb,
                    const float* __restrict__ Gl, float* __restrict__ Cb)
{
    __shared__ float A0s, A1s, Sdw[7], Sdh[7];
    int t = threadIdx.x;
    if (t == 0) {
        float a0 = 0.f, a1 = 0.f;
        for (int co = 0; co < 84; co++) {
            float aw = accw[co]; a0 += aw;
            float b = (co < 32) ? c3b[co] : ((co < 64) ? c5b[co - 32] : c7b[co - 64]);
            a1 += aw * b;
        }
        A0s = a0; A1s = a1;
    }
    if (t < 7)             { float s = 0.f; for (int xx = 0; xx < 13; xx++) s += dww[t * 13 + xx]; Sdw[t] = s; }
    if (t >= 8 && t < 15)  { int oh = t - 8; float s = 0.f; for (int y = 0; y < 13; y++) s += dhw[oh * 13 + y]; Sdh[oh] = s; }
    __syncthreads();
    if (t < 49) {
        int ow = t / 7, oh = t % 7;
        float g = 0.f;
        for (int c = 0; c < 512; c++) g += Gl[c * 49 + t];
        Cb[t] = A1s * Sdw[ow] * Sdh[oh] + A0s * (dwb[ow] * Sdh[oh] + dhb[oh]) + accb[0] + g;
    }
}

// ---------------- K_cw1: partial GEMM with inline LayerNorm  cw_partial = LN(x) x Gmat ----------------
__global__ __launch_bounds__(64) void kCw1(const float* __restrict__ x,
    const float* __restrict__ Gmat, float* __restrict__ part)
{
    __shared__ float As[64 * 53];
    __shared__ float Gs[49 * 68];
    const int b = blockIdx.x;
    const int nt = b >> 7, ks = b & 127;
    const int n0 = nt * 64;
    const int cq0 = ks * 196;
    const int t = threadIdx.x;
    const int ng = t >> 2, pg = t & 3;
    float acc[4][16];
    #pragma unroll
    for (int j = 0; j < 4; j++)
        #pragma unroll
        for (int m = 0; m < 16; m++) acc[j][m] = 0.f;
    for (int kk = 0; kk < 4; kk++) {
        const int kb = cq0 + kk * 49;
        for (int i = t; i < 3136; i += 64) { int nr = i / 49, kc = i % 49; As[nr * 53 + kc] = x[(size_t)(n0 + nr) * CQ + kb + kc]; }
        for (int i = t; i < 2401; i += 64) { Gs[(i / 49) * 68 + (i % 49)] = Gmat[(size_t)kb * 49 + i]; }
        __syncthreads();
        // inline LayerNorm on row t (each (n,c) row loaded by exactly one block)
        {
            float s = 0.f, ss = 0.f;
            for (int i = 0; i < 49; i++) { float v = As[t * 53 + i]; s += v; ss += v * v; }
            float mu = s * (1.f / 49.f);
            float var = ss * (1.f / 49.f) - mu * mu;
            float rs = 1.f / sqrtf(var + 1e-5f);
            for (int i = 0; i < 49; i++) As[t * 53 + i] = (As[t * 53 + i] - mu) * rs;
        }
        __syncthreads();
        for (int k = 0; k < 49; k++) {
            const float* gp = &Gs[k * 68 + 16 * pg];
            float4 g0 = *(const float4*)(gp + 0);
            float4 g1 = *(const float4*)(gp + 4);
            float4 g2 = *(const float4*)(gp + 8);
            float4 g3 = *(const float4*)(gp + 12);
            #pragma unroll
            for (int j = 0; j < 4; j++) {
                float a = As[(4 * ng + j) * 53 + k];
                acc[j][0]  += a * g0.x; acc[j][1]  += a * g0.y; acc[j][2]  += a * g0.z; acc[j][3]  += a * g0.w;
                acc[j][4]  += a * g1.x; acc[j][5]  += a * g1.y; acc[j][6]  += a * g1.z; acc[j][7]  += a * g1.w;
                acc[j][8]  += a * g2.x; acc[j][9]  += a * g2.y; acc[j][10] += a * g2.z; acc[j][11] += a * g2.w;
                acc[j][12] += a * g3.x; acc[j][13] += a * g3.y; acc[j][14] += a * g3.z; acc[j][15] += a * g3.w;
            }
        }
        __syncthreads();
    }
    #pragma unroll
    for (int j = 0; j < 4; j++) {
        int n = n0 + 4 * ng + j;
        #pragma unroll
        for (int m = 0; m < 16; m++) {
            int p = 16 * pg + m;
            if (p < 49) part[(size_t)ks * CQ + (size_t)n * 49 + p] = acc[j][m];
        }
    }
}

// ---------------- K_cw2: reduce partials + Cb ----------------
__global__ __launch_bounds__(256) void kCw2(const float* __restrict__ part, const float* __restrict__ Cb,
                                            float* __restrict__ cw)
{
    int o = blockIdx.x * 256 + threadIdx.x;
    if (o >= CQ) return;
    int p = o % 49;
    float s = Cb[p];
    for (int ks = 0; ks < 128; ks++) s += part[(size_t)ks * CQ + o];
    cw[o] = s;
}

// ---------------- K_main: fused norms + logits + softmax + mask + VLAD + out ----------------
__global__ __launch_bounds__(512) void kMain(const float* __restrict__ x,
    const float* __restrict__ convw, const float* __restrict__ convb,
    const float* __restrict__ cwg, const float* __restrict__ cent, float* __restrict__ out)
{
    __shared__ float xT[49 * XP];          // 101,136 B, l-major
    __shared__ float lg[64 * 52];          // logits -> mask in place
    __shared__ float ps[8 * 56];
    __shared__ float rn[49], cwl[49], cb[64], smax[49], sinv[49];
    __shared__ float pmx[49 * 8], psm[49 * 8];
    __shared__ float msL[64], ssq[64], scl[64];
    const int n = blockIdx.x;
    const int t = threadIdx.x;
    const int lane = t & 63;
    const int w = t >> 6;
    const float* xp = x + (size_t)n * CQ;
    // phase 1: load + transpose (float4 global reads, scalar LDS scatter)
    for (int i4 = t; i4 < 6272; i4 += 512) {
        float4 v = *(const float4*)(xp + i4 * 4);
        int i = i4 * 4;
        int c = i / 49, l = i - c * 49;
        float vv[4] = {v.x, v.y, v.z, v.w};
        #pragma unroll
        for (int j = 0; j < 4; j++) {
            xT[l * XP + c] = vv[j];
            l++; if (l == 49) { l = 0; c++; }
        }
    }
    if (t < 49) cwl[t] = cwg[n * 49 + t];
    if (t >= 64 && t < 128) cb[t - 64] = convb[t - 64];
    __syncthreads();
    // phase 2: rn[l] = 1/max(||x[:,l]||,eps); wave w covers channels [64w,64w+64)
    if (lane < 49) {
        const float* row = &xT[lane * XP + w * 64];
        float s = 0.f;
        #pragma unroll 4
        for (int c4 = 0; c4 < 16; c4++) {
            float4 v = *(const float4*)(row + c4 * 4);
            s += v.x * v.x + v.y * v.y + v.z * v.z + v.w * v.w;
        }
        ps[w * 56 + lane] = s;
    }
    __syncthreads();
    if (t < 49) {
        float s = 0.f;
        #pragma unroll
        for (int q = 0; q < 8; q++) s += ps[q * 56 + t];
        rn[t] = 1.f / fmaxf(sqrtf(s), 1e-12f);
    }
    __syncthreads();
    // phase 3: logits GEMM — wave w -> k-octet, lane -> l
    {
        const int kw = __builtin_amdgcn_readfirstlane(w);
        const int lr = (lane < 49) ? lane : 48;
        float a[8];
        #pragma unroll
        for (int j = 0; j < 8; j++) a[j] = 0.f;
        const float* xrow = &xT[lr * XP];
        #pragma unroll 4
        for (int c4 = 0; c4 < 128; c4++) {
            float4 xv = *(const float4*)(xrow + c4 * 4);
            #pragma unroll
            for (int j = 0; j < 8; j++) {
                float4 wv = *(const float4*)&convw[(size_t)(kw * 8 + j) * 512 + c4 * 4];
                a[j] += wv.x * xv.x + wv.y * xv.y + wv.z * xv.z + wv.w * xv.w;
            }
        }
        if (lane < 49) {
            float r = rn[lane];
            #pragma unroll
            for (int j = 0; j < 8; j++) lg[(kw * 8 + j) * 52 + lane] = a[j] * r + cb[kw * 8 + j];
        }
    }
    __syncthreads();
    // phase 4: softmax over k per l, then mask = sa*cw (msum), then *rn
    if (t < 392) {
        int l = t >> 3, kq = t & 7;
        float m = -3.402823466e38f;
        #pragma unroll
        for (int j = 0; j < 8; j++) m = fmaxf(m, lg[(kq * 8 + j) * 52 + l]);
        pmx[t] = m;
    }
    __syncthreads();
    if (t < 49) {
        float m = pmx[t * 8];
        #pragma unroll
        for (int q = 1; q < 8; q++) m = fmaxf(m, pmx[t * 8 + q]);
        smax[t] = m;
    }
    __syncthreads();
    if (t < 392) {
        int l = t >> 3, kq = t & 7;
        float m = smax[l], s = 0.f;
        #pragma unroll
        for (int j = 0; j < 8; j++) s += __expf(lg[(kq * 8 + j) * 52 + l] - m);
        psm[t] = s;
    }
    __syncthreads();
    if (t < 49) {
        float s = 0.f;
        #pragma unroll
        for (int q = 0; q < 8; q++) s += psm[t * 8 + q];
        sinv[t] = 1.f / s;
    }
    __syncthreads();
    if (t < 392) {
        int l = t >> 3, kq = t & 7;
        float m = smax[l], si = sinv[l] * cwl[l];
        #pragma unroll
        for (int j = 0; j < 8; j++) {
            int idx = (kq * 8 + j) * 52 + l;
            lg[idx] = __expf(lg[idx] - m) * si;   // mask_raw = sa*cw
        }
    }
    __syncthreads();
    if (t < 64) {
        float s = 0.f;
        for (int l = 0; l < 49; l++) s += lg[t * 52 + l];
        msL[t] = s;
    }
    __syncthreads();
    if (t < 392) {
        int l = t >> 3, kq = t & 7;
        float r = rn[l];
        #pragma unroll
        for (int j = 0; j < 8; j++) lg[(kq * 8 + j) * 52 + l] *= r;   // mk = sa*cw*rn
    }
    __syncthreads();
    // phase 5: VLAD — wave w -> k-octet; lane -> c tile {4*lane..+3} U {256+4*lane..+3}
    float acc[8][8];
    #pragma unroll
    for (int j = 0; j < 8; j++)
        #pragma unroll
        for (int ci = 0; ci < 8; ci++) acc[j][ci] = 0.f;
    const int c0 = lane * 4;
    #pragma unroll 7
    for (int l = 0; l < 49; l++) {
        float4 xa = *(const float4*)&xT[l * XP + c0];
        float4 xb = *(const float4*)&xT[l * XP + 256 + c0];
        #pragma unroll
        for (int j = 0; j < 8; j++) {
            float m = lg[(w * 8 + j) * 52 + l];
            acc[j][0] += m * xa.x; acc[j][1] += m * xa.y; acc[j][2] += m * xa.z; acc[j][3] += m * xa.w;
            acc[j][4] += m * xb.x; acc[j][5] += m * xb.y; acc[j][6] += m * xb.z; acc[j][7] += m * xb.w;
        }
    }
    // epilogue: centroid subtract, intra-norm, global norm
    float ssr[8];
    #pragma unroll
    for (int j = 0; j < 8; j++) {
        int k = w * 8 + j;
        float ms = msL[k];
        float4 ca = *(const float4*)&cent[(size_t)k * 512 + c0];
        float4 cbv = *(const float4*)&cent[(size_t)k * 512 + 256 + c0];
        acc[j][0] -= ca.x * ms; acc[j][1] -= ca.y * ms; acc[j][2] -= ca.z * ms; acc[j][3] -= ca.w * ms;
        acc[j][4] -= cbv.x * ms; acc[j][5] -= cbv.y * ms; acc[j][6] -= cbv.z * ms; acc[j][7] -= cbv.w * ms;
        float s = 0.f;
        #pragma unroll
        for (int ci = 0; ci < 8; ci++) s += acc[j][ci] * acc[j][ci];
        ssr[j] = s;
    }
    #pragma unroll
    for (int j = 0; j < 8; j++)
        for (int off = 32; off >= 1; off >>= 1) ssr[j] += __shfl_xor(ssr[j], off, 64);
    if (lane == 0) {
        #pragma unroll
        for (int j = 0; j < 8; j++) ssq[w * 8 + j] = ssr[j];
    }
    __syncthreads();
    if (t < 64) {
        float nrm = sqrtf(ssq[t]);
        float inv = 1.f / fmaxf(nrm, 1e-12f);
        float sk = nrm * inv;
        float g = sk * sk;
        #pragma unroll
        for (int off = 32; off >= 1; off >>= 1) g += __shfl_xor(g, off, 64);
        scl[t] = inv * (1.f / fmaxf(sqrtf(g), 1e-12f));
    }
    __syncthreads();
    #pragma unroll
    for (int j = 0; j < 8; j++) {
        int k = w * 8 + j;
        float s2 = scl[k];
        float4 o1 = make_float4(acc[j][0] * s2, acc[j][1] * s2, acc[j][2] * s2, acc[j][3] * s2);
        float4 o2 = make_float4(acc[j][4] * s2, acc[j][5] * s2, acc[j][6] * s2, acc[j][7] * s2);
        *(float4*)&out[(size_t)n * 32768 + (size_t)k * 512 + c0] = o1;
        *(float4*)&out[(size_t)n * 32768 + (size_t)k * 512 + 256 + c0] = o2;
    }
}

extern "C" void kernel_launch(void* const* d_in, const int* in_sizes, int n_in,
                              void* d_out, int out_size, void* d_ws, size_t ws_size,
                              hipStream_t stream)
{
    const float* x     = (const float*)d_in[0];
    const float* cent  = (const float*)d_in[1];
    const float* convw = (const float*)d_in[2];
    const float* convb = (const float*)d_in[3];
    const float* lnw   = (const float*)d_in[4];
    const float* lnb   = (const float*)d_in[5];
    const float* c3w   = (const float*)d_in[6];
    const float* c3b   = (const float*)d_in[7];
    const float* c5w   = (const float*)d_in[8];
    const float* c5b   = (const float*)d_in[9];
    const float* c7w   = (const float*)d_in[10];
    const float* c7b   = (const float*)d_in[11];
    const float* dww   = (const float*)d_in[12];
    const float* dwb   = (const float*)d_in[13];
    const float* dhw   = (const float*)d_in[14];
    const float* dhb   = (const float*)d_in[15];
    const float* accw  = (const float*)d_in[16];
    const float* accb  = (const float*)d_in[17];
    float* out = (float*)d_out;

    char* ws = (char*)d_ws;
    float* Gmat = (float*)(ws);                 // 512*2401*4 = 4,917,248
    float* Gl   = (float*)(ws + 4917248);       // 512*49*4  = 100,352
    float* Cb   = (float*)(ws + 5017600);       // 256
    float* cw   = (float*)(ws + 5017856);       // 512*49*4  = 100,352
    float* part = (float*)(ws + 5118208);       // 128*25088*4 = 12,845,056 (end ~18MB)

    kG   <<<512,  256, 0, stream>>>(c3w, c5w, c7w, dww, dhw, accw, lnw, lnb, Gmat, Gl);
    kCb  <<<1,    64,  0, stream>>>(c3b, c5b, c7b, dww, dwb, dhw, dhb, accw, accb, Gl, Cb);
    kCw1 <<<1024, 64,  0, stream>>>(x, Gmat, part);
    kCw2 <<<98,   256, 0, stream>>>(part, Cb, cw);
    kMain<<<512,  512, 0, stream>>>(x, convw, convb, cw, cent, out);
}